// Round 18
// baseline (494.550 us; speedup 1.0000x reference)
//
#include <hip/hip_runtime.h>
#include <stdint.h>

typedef unsigned short u16;
typedef __attribute__((ext_vector_type(8))) short bf16x8;
typedef __attribute__((ext_vector_type(4))) float f32x4;

// Fast exp path: raw v_exp_f32 (exp2) if the builtin exists (compiler handles
// trans-op hazards); else native __expf. Scale constants pair with the choice.
#if __has_builtin(__builtin_amdgcn_exp2f)
  #define ATTN_EXP(x) __builtin_amdgcn_exp2f(x)
  #define ATTN_QSC 0.12751746f      // log2(e)/sqrt(128)
  #define ATTN_NOFF -11.5415603f    // -8*log2(e)
#else
  #define ATTN_EXP(x) __expf(x)
  #define ATTN_QSC 0.08838834764831845f  // 1/sqrt(128)
  #define ATTN_NOFF -8.0f
#endif

__device__ __forceinline__ u16 f2bf(float f) {
  uint32_t x = __float_as_uint(f);
  x += 0x7fffu + ((x >> 16) & 1u);
  return (u16)(x >> 16);
}
__device__ __forceinline__ float bf2f(u16 u) {
  return __uint_as_float(((uint32_t)u) << 16);
}
__device__ __forceinline__ void gload_lds16(const void* g, void* l) {
  __builtin_amdgcn_global_load_lds(
      (const __attribute__((address_space(1))) void*)g,
      (__attribute__((address_space(3))) void*)l, 16, 0, 0);
}

// rope rotate one C-element via partner lane (cols are lane-adjacent)
__device__ __forceinline__ float rope_rot(float a, int col, int srow,
                                          const float* __restrict__ cosT,
                                          const float* __restrict__ sinT) {
  float p = __shfl_xor(a, 1, 64);
  int d = (col & 127) >> 1;
  float c = cosT[srow * 64 + d];
  float sn = sinT[srow * 64 + d];
  return (col & 1) ? (p * sn + a * c) : (a * c - p * sn);
}

// ---------- elementwise f32 -> bf16 (4 elems/thread) ----------
__global__ __launch_bounds__(256) void cvt_kernel(const float* __restrict__ x,
                                                  u16* __restrict__ y) {
  int i = blockIdx.x * 256 + threadIdx.x;
  float4 v = ((const float4*)x)[i];
  ushort4 o = make_ushort4(f2bf(v.x), f2bf(v.y), f2bf(v.z), f2bf(v.w));
  ((ushort4*)y)[i] = o;
}

// ---------- transpose + convert: W[K][N] f32 -> Wt[N][K] bf16 ----------
__global__ __launch_bounds__(256) void transpose_cvt(const float* __restrict__ W,
                                                     u16* __restrict__ Wt,
                                                     int Kd, int Nd) {
  __shared__ float t[32][33];
  int k0 = blockIdx.y * 32, n0 = blockIdx.x * 32;
  int tx = threadIdx.x, ty = threadIdx.y;
  #pragma unroll
  for (int i = ty; i < 32; i += 8)
    t[i][tx] = W[(size_t)(k0 + i) * Nd + n0 + tx];
  __syncthreads();
  #pragma unroll
  for (int i = ty; i < 32; i += 8)
    Wt[(size_t)(n0 + i) * Kd + k0 + tx] = f2bf(t[tx][i]);
}

// ---------- fused K+V projection GEMM v2: 128^2 tile, v5 read-ahead schedule ----------
__global__ __launch_bounds__(256, 2) void gemm_kv(const u16* __restrict__ A,
                                                  const u16* __restrict__ Bt,
                                                  u16* __restrict__ Kout,
                                                  u16* __restrict__ Vt,
                                                  const float* __restrict__ cosT,
                                                  const float* __restrict__ sinT) {
  const int K = 4096;
  const int NK = 64;
  __shared__ __attribute__((aligned(16))) u16 sA[3][128 * 64];
  __shared__ __attribute__((aligned(16))) u16 sB[2][128 * 64];
  const int tid = threadIdx.x;
  const int wave = tid >> 6, lane = tid & 63;
  const int lr = lane & 15, lq = lane >> 4;
  int lin = blockIdx.y * gridDim.x + blockIdx.x;
  int cpx = (gridDim.x * gridDim.y) >> 3;
  int swz = (lin & 7) * cpx + (lin >> 3);
  const int bm = (swz >> 4) * 128, bn = (swz & 15) * 128;
  const int wm = (wave >> 1) * 64, wn = (wave & 1) * 64;

  f32x4 acc[4][4] = {};

  auto stageA = [&](int j) {
    u16* dst = &sA[j % 3][0];
    #pragma unroll
    for (int c = 0; c < 4; ++c) {
      int e = (c * 256 + tid) * 8;
      int r = e >> 6, col = e & 63;
      gload_lds16(A + (size_t)(bm + r) * K + j * 64 + (col ^ ((r & 7) << 3)), dst + e);
    }
  };
  auto stageB = [&](int j) {
    u16* dst = &sB[j & 1][0];
    #pragma unroll
    for (int c = 0; c < 4; ++c) {
      int e = (c * 256 + tid) * 8;
      int r = e >> 6, col = e & 63;
      gload_lds16(Bt + (size_t)(bn + r) * K + j * 64 + (col ^ ((r & 7) << 3)), dst + e);
    }
  };
  auto readA = [&](bf16x8* af, const u16* a_, int ks) {
    #pragma unroll
    for (int mf = 0; mf < 4; ++mf) {
      int row = wm + mf * 16 + lr;
      af[mf] = *(const bf16x8*)(a_ + row * 64 + ((ks * 32 + lq * 8) ^ ((row & 7) << 3)));
    }
  };
  auto readB = [&](bf16x8* bfv, const u16* b_, int ks) {
    #pragma unroll
    for (int nf = 0; nf < 4; ++nf) {
      int row = wn + nf * 16 + lr;
      bfv[nf] = *(const bf16x8*)(b_ + row * 64 + ((ks * 32 + lq * 8) ^ ((row & 7) << 3)));
    }
  };

  bf16x8 afP[4], bfP[4], afQ[4], bfQ[4];

  stageA(0); stageB(0); stageA(1); stageB(1);
  asm volatile("s_waitcnt vmcnt(8)" ::: "memory");
  asm volatile("s_barrier" ::: "memory");
  readA(afP, sA[0], 0); readB(bfP, sB[0], 0);

  for (int j = 0; j < NK; ++j) {
    const u16* a_ = sA[j % 3];
    const u16* b_ = sB[j & 1];
    const u16* an = sA[(j + 1) % 3];
    const u16* bn_ = sB[(j + 1) & 1];
    readA(afQ, a_, 1); readB(bfQ, b_, 1);
    if (j + 2 < NK) stageA(j + 2);
    asm volatile("s_waitcnt lgkmcnt(8)" ::: "memory");
    __builtin_amdgcn_sched_barrier(0);
    __builtin_amdgcn_s_setprio(1);
    #pragma unroll
    for (int mf = 0; mf < 4; ++mf)
      #pragma unroll
      for (int nf = 0; nf < 4; ++nf)
        acc[mf][nf] = __builtin_amdgcn_mfma_f32_16x16x32_bf16(afP[mf], bfP[nf],
                                                              acc[mf][nf], 0, 0, 0);
    __builtin_amdgcn_s_setprio(0);
    if (j + 2 < NK) asm volatile("s_waitcnt vmcnt(4)" ::: "memory");
    else            asm volatile("s_waitcnt vmcnt(0)" ::: "memory");
    asm volatile("s_barrier" ::: "memory");
    readA(afP, an, 0); readB(bfP, bn_, 0);
    if (j + 2 < NK) stageB(j + 2);
    asm volatile("s_waitcnt lgkmcnt(8)" ::: "memory");
    __builtin_amdgcn_sched_barrier(0);
    __builtin_amdgcn_s_setprio(1);
    #pragma unroll
    for (int mf = 0; mf < 4; ++mf)
      #pragma unroll
      for (int nf = 0; nf < 4; ++nf)
        acc[mf][nf] = __builtin_amdgcn_mfma_f32_16x16x32_bf16(afQ[mf], bfQ[nf],
                                                              acc[mf][nf], 0, 0, 0);
    __builtin_amdgcn_s_setprio(0);
  }

  #pragma unroll
  for (int i = 0; i < 4; ++i) {
    #pragma unroll
    for (int j = 0; j < 4; ++j) {
      int colg = bn + wn + j * 16 + lr;
      if (bn < 1024) {  // K head, fused RoPE (block-uniform branch)
        #pragma unroll
        for (int r = 0; r < 4; ++r) {
          int row = bm + wm + i * 16 + lq * 4 + r;
          float o = rope_rot(acc[i][j][r], colg, row & 2047, cosT, sinT);
          Kout[(size_t)row * 1024 + colg] = f2bf(o);
        }
      } else {  // V -> V^T pack
        int col = colg - 1024;
        int row0 = bm + wm + i * 16 + lq * 4;
        int bb = row0 >> 11, s = row0 & 2047;
        ushort4 pk = make_ushort4(f2bf(acc[i][j][0]), f2bf(acc[i][j][1]),
                                  f2bf(acc[i][j][2]), f2bf(acc[i][j][3]));
        *(ushort4*)(Vt + ((size_t)bb * 1024 + col) * 2048 + s) = pk;
      }
    }
  }
}

// ---------- 256^2-tile GEMM v5 (best measured): read-ahead + deep slack ----------
template <int EPI, bool ROPE>
__global__ __launch_bounds__(512, 2) void gemm256(const u16* __restrict__ A,
                                                  const u16* __restrict__ Bt,
                                                  void* __restrict__ Cout,
                                                  int M, int N, int K,
                                                  const float* __restrict__ cosT,
                                                  const float* __restrict__ sinT,
                                                  float post) {
  __shared__ __attribute__((aligned(16))) u16 sA[3][256 * 64];
  __shared__ __attribute__((aligned(16))) u16 sB[2][256 * 64];
  const int tid = threadIdx.x;
  const int wid = tid >> 6, lane = tid & 63;
  const int lr = lane & 15, lq = lane >> 4;
  const int nbn = N >> 8;
  int lin = blockIdx.y * gridDim.x + blockIdx.x;
  int cpx = (gridDim.x * gridDim.y) >> 3;
  int swz = (lin & 7) * cpx + (lin >> 3);
  const int bm = (swz / nbn) * 256, bn = (swz % nbn) * 256;
  const int wrow = (wid >> 2) * 128, wcol = (wid & 3) * 64;
  const int NK = K >> 6;

  f32x4 acc[8][4] = {};

  auto stageA = [&](int j) {
    u16* dst = &sA[j % 3][0];
    #pragma unroll
    for (int c = 0; c < 4; ++c) {
      int e = (c * 512 + tid) * 8;
      int r = e >> 6, col = e & 63;
      gload_lds16(A + (size_t)(bm + r) * K + j * 64 + (col ^ ((r & 7) << 3)), dst + e);
    }
  };
  auto stageB = [&](int j) {
    u16* dst = &sB[j & 1][0];
    #pragma unroll
    for (int c = 0; c < 4; ++c) {
      int e = (c * 512 + tid) * 8;
      int r = e >> 6, col = e & 63;
      gload_lds16(Bt + (size_t)(bn + r) * K + j * 64 + (col ^ ((r & 7) << 3)), dst + e);
    }
  };
  auto readA = [&](bf16x8* af, const u16* a_, int ks) {
    #pragma unroll
    for (int mf = 0; mf < 8; ++mf) {
      int row = wrow + mf * 16 + lr;
      af[mf] = *(const bf16x8*)(a_ + row * 64 + ((ks * 32 + lq * 8) ^ ((row & 7) << 3)));
    }
  };
  auto readB = [&](bf16x8* bfv, const u16* b_, int ks) {
    #pragma unroll
    for (int nf = 0; nf < 4; ++nf) {
      int row = wcol + nf * 16 + lr;
      bfv[nf] = *(const bf16x8*)(b_ + row * 64 + ((ks * 32 + lq * 8) ^ ((row & 7) << 3)));
    }
  };

  bf16x8 afP[8], bfP[4], afQ[8], bfQ[4];

  stageB(0); stageA(0); stageA(1); stageB(1);
  asm volatile("s_waitcnt vmcnt(8)" ::: "memory");
  asm volatile("s_barrier" ::: "memory");
  readA(afP, sA[0], 0); readB(bfP, sB[0], 0);  // frags (0,0)

  for (int j = 0; j < NK; ++j) {
    const u16* a_ = sA[j % 3];
    const u16* b_ = sB[j & 1];
    const u16* an = sA[(j + 1) % 3];
    const u16* bn = sB[(j + 1) & 1];
    readA(afQ, a_, 1); readB(bfQ, b_, 1);
    if (j + 2 < NK) stageA(j + 2);
    asm volatile("s_waitcnt lgkmcnt(12)" ::: "memory");
    __builtin_amdgcn_sched_barrier(0);
    __builtin_amdgcn_s_setprio(1);
    #pragma unroll
    for (int mf = 0; mf < 8; ++mf)
      #pragma unroll
      for (int nf = 0; nf < 4; ++nf)
        acc[mf][nf] = __builtin_amdgcn_mfma_f32_16x16x32_bf16(afP[mf], bfP[nf],
                                                              acc[mf][nf], 0, 0, 0);
    __builtin_amdgcn_s_setprio(0);
    if (j + 2 < NK) asm volatile("s_waitcnt vmcnt(4)" ::: "memory");
    else            asm volatile("s_waitcnt vmcnt(0)" ::: "memory");
    asm volatile("s_barrier" ::: "memory");
    readA(afP, an, 0); readB(bfP, bn, 0);
    if (j + 2 < NK) stageB(j + 2);
    asm volatile("s_waitcnt lgkmcnt(12)" ::: "memory");
    __builtin_amdgcn_sched_barrier(0);
    __builtin_amdgcn_s_setprio(1);
    #pragma unroll
    for (int mf = 0; mf < 8; ++mf)
      #pragma unroll
      for (int nf = 0; nf < 4; ++nf)
        acc[mf][nf] = __builtin_amdgcn_mfma_f32_16x16x32_bf16(afQ[mf], bfQ[nf],
                                                              acc[mf][nf], 0, 0, 0);
    __builtin_amdgcn_s_setprio(0);
  }

  #pragma unroll
  for (int mf = 0; mf < 8; ++mf) {
    #pragma unroll
    for (int nf = 0; nf < 4; ++nf) {
      #pragma unroll
      for (int r = 0; r < 4; ++r) {
        int row = bm + wrow + mf * 16 + lq * 4 + r;
        int col = bn + wcol + nf * 16 + lr;
        if (ROPE) {
          float o = rope_rot(acc[mf][nf][r], col, row & 2047, cosT, sinT);
          ((u16*)Cout)[(size_t)row * N + col] = f2bf(o * post);
        } else if (EPI == 0) {
          ((u16*)Cout)[(size_t)row * N + col] = f2bf(acc[mf][nf][r]);
        } else {
          ((float*)Cout)[(size_t)row * N + col] = acc[mf][nf][r];
        }
      }
    }
  }
}

// ---------- flash attention: GQA head-paired blocks (8 waves, 4/SIMD) ----------
// 512-thread block = (b, kvh, head-pair hp, q-pair p): waves 0-3 -> head h0,
// waves 4-7 -> head h1 (same kvh -> shared K/V; same p -> identical loop bound,
// perfect balance). K/V staged ONCE per block (HBM/L2 traffic halves) and LDS
// 80KB keeps 2 blocks/CU -> 16 waves/CU = 4/SIMD (was 2): double TLP for this
// latency-bound kernel. Per-head math identical to r17 (swapped-QK + cvt_pk).
__global__ __launch_bounds__(512, 2) void attn_kernel(const u16* __restrict__ Q,
                                                      const u16* __restrict__ Kb,
                                                      const u16* __restrict__ Vt,
                                                      u16* __restrict__ O) {
  __shared__ __attribute__((aligned(16))) u16 sK[2][64 * 128];
  __shared__ __attribute__((aligned(16))) u16 sV[2][128 * 64];
  __shared__ __attribute__((aligned(16))) u16 sP[8][16 * 64];
  const int tid = threadIdx.x;
  const int wave = tid >> 6, lane = tid & 63;
  const int lr = lane & 15, lq = lane >> 4;
  const int w4 = wave & 3;        // per-q-tile wave within the head group
  const int hl = wave >> 2;       // 0 or 1: which head of the pair
  const int p = blockIdx.x & 15;
  const int hp = (blockIdx.x >> 4) & 1;
  const int kvh = (blockIdx.x >> 5) & 7;
  const int b = blockIdx.x >> 8;
  const int h = kvh * 4 + hp * 2 + hl;
  const int qtA = p, qtB = 31 - p;
  const int q0A = qtA * 64 + w4 * 16;
  const int q0B = qtB * 64 + w4 * 16;
  const float NOFF = ATTN_NOFF;

  bf16x8 qfA[4], qfB[4];
  {
    const u16* qa = Q + (size_t)(b * 2048 + q0A + lr) * 4096 + h * 128 + lq * 8;
    const u16* qb = Q + (size_t)(b * 2048 + q0B + lr) * 4096 + h * 128 + lq * 8;
    #pragma unroll
    for (int ks = 0; ks < 4; ++ks) {
      qfA[ks] = *(const bf16x8*)(qa + ks * 32);
      qfB[ks] = *(const bf16x8*)(qb + ks * 32);
    }
  }

  const u16* kbase = Kb + (size_t)b * 2048 * 1024 + kvh * 128;
  const u16* vbase = Vt + (size_t)(b * 1024 + kvh * 128) * 2048;

  // 8 waves cover K(16KB) with 2 chunks each, V likewise
  auto stage = [&](int kt, int bsel) {
    #pragma unroll
    for (int c = 0; c < 2; ++c) {
      int chunk = wave * 2 + c;
      int eo = chunk * 512 + lane * 8;
      int rk = eo >> 7, ck = eo & 127;
      int cks = ck ^ ((rk & 7) << 3);
      gload_lds16(kbase + (size_t)(kt * 64 + rk) * 1024 + cks,
                  (u16*)sK[bsel] + chunk * 512);
      int rv = eo >> 6, cv = eo & 63;
      int cvs = cv ^ ((rv & 7) << 3);
      gload_lds16(vbase + (size_t)rv * 2048 + kt * 64 + cvs,
                  (u16*)sV[bsel] + chunk * 512);
    }
  };

  f32x4 oA[8] = {}, oB[8] = {};
  float lA = 0.f, lB = 0.f;  // per-lane partial row-sum for q = lr

  stage(0, 0);
  __syncthreads();
  int buf = 0;
  for (int kt = 0; kt <= qtB; ++kt) {
    if (kt < qtB) stage(kt + 1, buf ^ 1);
    const u16* kb_ = sK[buf];
    const u16* vb_ = sV[buf];
    const bool doA = (kt <= qtA);

    f32x4 sAacc[4], sBacc[4];
    #pragma unroll
    for (int nf = 0; nf < 4; ++nf) {
      sAacc[nf] = (f32x4){NOFF, NOFF, NOFF, NOFF};
      sBacc[nf] = (f32x4){NOFF, NOFF, NOFF, NOFF};
    }
    __builtin_amdgcn_s_setprio(1);
    #pragma unroll
    for (int ks = 0; ks < 4; ++ks) {
      bf16x8 kf[4];
      #pragma unroll
      for (int nf = 0; nf < 4; ++nf) {
        int row = nf * 16 + lr;
        kf[nf] = *(const bf16x8*)(kb_ + row * 128 + ((ks * 32 + lq * 8) ^ ((row & 7) << 3)));
      }
      // swapped: lane holds S[q=lr][key=nf*16+lq*4+r]
      #pragma unroll
      for (int nf = 0; nf < 4; ++nf)
        sBacc[nf] = __builtin_amdgcn_mfma_f32_16x16x32_bf16(kf[nf], qfB[ks], sBacc[nf], 0, 0, 0);
      if (doA) {
        #pragma unroll
        for (int nf = 0; nf < 4; ++nf)
          sAacc[nf] = __builtin_amdgcn_mfma_f32_16x16x32_bf16(kf[nf], qfA[ks], sAacc[nf], 0, 0, 0);
      }
    }
    __builtin_amdgcn_s_setprio(0);

    auto sm_pv = [&](f32x4* sacc, float& lsum, f32x4* o, int qt, int q0) {
      float ls = 0.f;
      const bool diag = (kt == qt);
      #pragma unroll
      for (int nf = 0; nf < 4; ++nf) {
        float v0 = ATTN_EXP(sacc[nf][0]);
        float v1 = ATTN_EXP(sacc[nf][1]);
        float v2 = ATTN_EXP(sacc[nf][2]);
        float v3 = ATTN_EXP(sacc[nf][3]);
        if (diag) {
          int kb0 = kt * 64 + nf * 16 + lq * 4;
          int q = q0 + lr;
          if (kb0 + 0 > q) v0 = 0.f;
          if (kb0 + 1 > q) v1 = 0.f;
          if (kb0 + 2 > q) v2 = 0.f;
          if (kb0 + 3 > q) v3 = 0.f;
        }
        ls += (v0 + v1) + (v2 + v3);
        uint32_t p01, p23;
        asm("v_cvt_pk_bf16_f32 %0, %1, %2" : "=v"(p01) : "v"(v0), "v"(v1));
        asm("v_cvt_pk_bf16_f32 %0, %1, %2" : "=v"(p23) : "v"(v2), "v"(v3));
        uint32_t* dst = (uint32_t*)((char*)sP[wave] +
                          ((lr * 128 + nf * 32 + lq * 8) ^ ((lr & 7) << 4)));
        dst[0] = p01;
        dst[1] = p23;
      }
      lsum += ls;
      __builtin_amdgcn_s_setprio(1);
      #pragma unroll
      for (int ks = 0; ks < 2; ++ks) {
        bf16x8 pa = *(const bf16x8*)((const char*)sP[wave] +
                        ((lr * 128 + ks * 64 + lq * 16) ^ ((lr & 7) << 4)));
        #pragma unroll
        for (int df = 0; df < 8; ++df) {
          int row = df * 16 + lr;
          bf16x8 vb = *(const bf16x8*)(vb_ + row * 64 + ((ks * 32 + lq * 8) ^ ((row & 7) << 3)));
          o[df] = __builtin_amdgcn_mfma_f32_16x16x32_bf16(pa, vb, o[df], 0, 0, 0);
        }
      }
      __builtin_amdgcn_s_setprio(0);
    };

    if (doA) sm_pv(sAacc, lA, oA, qtA, q0A);
    sm_pv(sBacc, lB, oB, qtB, q0B);

    __syncthreads();
    buf ^= 1;
  }

  float tA = lA, tB = lB;
  tA += __shfl_xor(tA, 16, 64); tB += __shfl_xor(tB, 16, 64);
  tA += __shfl_xor(tA, 32, 64); tB += __shfl_xor(tB, 32, 64);
  tA = 1.f / tA; tB = 1.f / tB;
  float liA[4], liB[4];
  #pragma unroll
  for (int r = 0; r < 4; ++r) {
    liA[r] = __shfl(tA, lq * 4 + r, 64);
    liB[r] = __shfl(tB, lq * 4 + r, 64);
  }
  #pragma unroll
  for (int df = 0; df < 8; ++df) {
    #pragma unroll
    for (int r = 0; r < 4; ++r) {
      int iqA = q0A + lq * 4 + r;
      int iqB = q0B + lq * 4 + r;
      O[(size_t)(b * 2048 + iqA) * 4096 + h * 128 + df * 16 + lr] = f2bf(oA[df][r] * liA[r]);
      O[(size_t)(b * 2048 + iqB) * 4096 + h * 128 + df * 16 + lr] = f2bf(oB[df][r] * liB[r]);
    }
  }
}

extern "C" void kernel_launch(void* const* d_in, const int* in_sizes, int n_in,
                              void* d_out, int out_size, void* d_ws, size_t ws_size,
                              hipStream_t stream) {
  (void)in_sizes; (void)n_in; (void)out_size;
  const float* x    = (const float*)d_in[0];
  const float* cosT = (const float*)d_in[1];
  const float* sinT = (const float*)d_in[2];
  const float* wq   = (const float*)d_in[4];
  const float* wk   = (const float*)d_in[5];
  const float* wv   = (const float*)d_in[6];
  const float* wo   = (const float*)d_in[7];
  float* out = (float*)d_out;
  char* ws = (char*)d_ws;

  const size_t WS_NEEDED = 201326592;  // 192 MiB
  if (ws_size < WS_NEEDED) return;

  u16* xb   = (u16*)(ws);                 // [4096][4096]
  u16* wqt  = (u16*)(ws + 33554432ULL);   // [4096][4096]
  u16* wkvt = (u16*)(ws + 67108864ULL);   // [2048][4096]
  u16* wot  = (u16*)(ws + 83886080ULL);   // [4096][4096]
  u16* Qb   = (u16*)(ws + 117440512ULL);  // [4096][4096]
  u16* Kbf  = (u16*)(ws + 150994944ULL);  // [4096][1024]
  u16* Vt   = (u16*)(ws + 159383552ULL);  // [2][1024][2048]
  u16* Ob   = (u16*)(ws + 167772160ULL);  // [4096][4096]

  const float QSC = ATTN_QSC;  // pairs with ATTN_NOFF / ATTN_EXP

  cvt_kernel<<<16384, 256, 0, stream>>>(x, xb);
  transpose_cvt<<<dim3(128, 128), dim3(32, 8), 0, stream>>>(wq, wqt, 4096, 4096);
  transpose_cvt<<<dim3(32, 128),  dim3(32, 8), 0, stream>>>(wk, wkvt, 4096, 1024);
  transpose_cvt<<<dim3(32, 128),  dim3(32, 8), 0, stream>>>(wv, wkvt + 1024ULL * 4096, 4096, 1024);
  transpose_cvt<<<dim3(128, 128), dim3(32, 8), 0, stream>>>(wo, wot, 4096, 4096);

  // Q projection with fused RoPE + prescale
  gemm256<0, true><<<dim3(16, 16), 512, 0, stream>>>(xb, wqt, Qb, 4096, 4096, 4096,
                                                     cosT, sinT, QSC);
  // fused K (RoPE) + V (transposed) projections
  gemm_kv<<<dim3(16, 32), 256, 0, stream>>>(xb, wkvt, Kbf, Vt, cosT, sinT);

  attn_kernel<<<512, 512, 0, stream>>>(Qb, Kbf, Vt, Ob);

  gemm256<2, false><<<dim3(16, 16), 512, 0, stream>>>(Ob, wot, out, 4096, 4096, 4096,
                                                      nullptr, nullptr, 1.0f);
}

// Round 19
// 484.554 us; speedup vs baseline: 1.0206x; 1.0206x over previous
//
#include <hip/hip_runtime.h>
#include <stdint.h>

typedef unsigned short u16;
typedef __attribute__((ext_vector_type(8))) short bf16x8;
typedef __attribute__((ext_vector_type(4))) float f32x4;

// Fast exp path: raw v_exp_f32 (exp2) if the builtin exists (compiler handles
// trans-op hazards); else native __expf. Scale constants pair with the choice.
#if __has_builtin(__builtin_amdgcn_exp2f)
  #define ATTN_EXP(x) __builtin_amdgcn_exp2f(x)
  #define ATTN_QSC 0.12751746f      // log2(e)/sqrt(128)
  #define ATTN_NOFF -11.5415603f    // -8*log2(e)
#else
  #define ATTN_EXP(x) __expf(x)
  #define ATTN_QSC 0.08838834764831845f  // 1/sqrt(128)
  #define ATTN_NOFF -8.0f
#endif

__device__ __forceinline__ u16 f2bf(float f) {
  uint32_t x = __float_as_uint(f);
  x += 0x7fffu + ((x >> 16) & 1u);
  return (u16)(x >> 16);
}
__device__ __forceinline__ float bf2f(u16 u) {
  return __uint_as_float(((uint32_t)u) << 16);
}
__device__ __forceinline__ void gload_lds16(const void* g, void* l) {
  __builtin_amdgcn_global_load_lds(
      (const __attribute__((address_space(1))) void*)g,
      (__attribute__((address_space(3))) void*)l, 16, 0, 0);
}

// rope rotate one C-element via partner lane (cols are lane-adjacent)
__device__ __forceinline__ float rope_rot(float a, int col, int srow,
                                          const float* __restrict__ cosT,
                                          const float* __restrict__ sinT) {
  float p = __shfl_xor(a, 1, 64);
  int d = (col & 127) >> 1;
  float c = cosT[srow * 64 + d];
  float sn = sinT[srow * 64 + d];
  return (col & 1) ? (p * sn + a * c) : (a * c - p * sn);
}

// ---------- elementwise f32 -> bf16 (4 elems/thread) ----------
__global__ __launch_bounds__(256) void cvt_kernel(const float* __restrict__ x,
                                                  u16* __restrict__ y) {
  int i = blockIdx.x * 256 + threadIdx.x;
  float4 v = ((const float4*)x)[i];
  ushort4 o = make_ushort4(f2bf(v.x), f2bf(v.y), f2bf(v.z), f2bf(v.w));
  ((ushort4*)y)[i] = o;
}

// ---------- dual transpose+convert: two W[K][N] f32 -> Wt[N][K] bf16 in one grid ----------
// by < half: (W0 -> T0); else (W1 -> T1). Per-block work identical to the single version.
__global__ __launch_bounds__(256) void transpose_cvt2(const float* __restrict__ W0,
                                                      u16* __restrict__ T0,
                                                      const float* __restrict__ W1,
                                                      u16* __restrict__ T1,
                                                      int Kd, int Nd, int halfY) {
  __shared__ float t[32][33];
  int byr = blockIdx.y;
  const float* W = (byr < halfY) ? W0 : W1;
  u16* Wt = (byr < halfY) ? T0 : T1;
  if (byr >= halfY) byr -= halfY;
  int k0 = byr * 32, n0 = blockIdx.x * 32;
  int tx = threadIdx.x, ty = threadIdx.y;
  #pragma unroll
  for (int i = ty; i < 32; i += 8)
    t[i][tx] = W[(size_t)(k0 + i) * Nd + n0 + tx];
  __syncthreads();
  #pragma unroll
  for (int i = ty; i < 32; i += 8)
    Wt[(size_t)(n0 + i) * Kd + k0 + tx] = f2bf(t[tx][i]);
}

// ---------- fused K+V projection GEMM v2: 128^2 tile, v5 read-ahead schedule ----------
__global__ __launch_bounds__(256, 2) void gemm_kv(const u16* __restrict__ A,
                                                  const u16* __restrict__ Bt,
                                                  u16* __restrict__ Kout,
                                                  u16* __restrict__ Vt,
                                                  const float* __restrict__ cosT,
                                                  const float* __restrict__ sinT) {
  const int K = 4096;
  const int NK = 64;
  __shared__ __attribute__((aligned(16))) u16 sA[3][128 * 64];
  __shared__ __attribute__((aligned(16))) u16 sB[2][128 * 64];
  const int tid = threadIdx.x;
  const int wave = tid >> 6, lane = tid & 63;
  const int lr = lane & 15, lq = lane >> 4;
  int lin = blockIdx.y * gridDim.x + blockIdx.x;
  int cpx = (gridDim.x * gridDim.y) >> 3;
  int swz = (lin & 7) * cpx + (lin >> 3);
  const int bm = (swz >> 4) * 128, bn = (swz & 15) * 128;
  const int wm = (wave >> 1) * 64, wn = (wave & 1) * 64;

  f32x4 acc[4][4] = {};

  auto stageA = [&](int j) {
    u16* dst = &sA[j % 3][0];
    #pragma unroll
    for (int c = 0; c < 4; ++c) {
      int e = (c * 256 + tid) * 8;
      int r = e >> 6, col = e & 63;
      gload_lds16(A + (size_t)(bm + r) * K + j * 64 + (col ^ ((r & 7) << 3)), dst + e);
    }
  };
  auto stageB = [&](int j) {
    u16* dst = &sB[j & 1][0];
    #pragma unroll
    for (int c = 0; c < 4; ++c) {
      int e = (c * 256 + tid) * 8;
      int r = e >> 6, col = e & 63;
      gload_lds16(Bt + (size_t)(bn + r) * K + j * 64 + (col ^ ((r & 7) << 3)), dst + e);
    }
  };
  auto readA = [&](bf16x8* af, const u16* a_, int ks) {
    #pragma unroll
    for (int mf = 0; mf < 4; ++mf) {
      int row = wm + mf * 16 + lr;
      af[mf] = *(const bf16x8*)(a_ + row * 64 + ((ks * 32 + lq * 8) ^ ((row & 7) << 3)));
    }
  };
  auto readB = [&](bf16x8* bfv, const u16* b_, int ks) {
    #pragma unroll
    for (int nf = 0; nf < 4; ++nf) {
      int row = wn + nf * 16 + lr;
      bfv[nf] = *(const bf16x8*)(b_ + row * 64 + ((ks * 32 + lq * 8) ^ ((row & 7) << 3)));
    }
  };

  bf16x8 afP[4], bfP[4], afQ[4], bfQ[4];

  stageA(0); stageB(0); stageA(1); stageB(1);
  asm volatile("s_waitcnt vmcnt(8)" ::: "memory");
  asm volatile("s_barrier" ::: "memory");
  readA(afP, sA[0], 0); readB(bfP, sB[0], 0);

  for (int j = 0; j < NK; ++j) {
    const u16* a_ = sA[j % 3];
    const u16* b_ = sB[j & 1];
    const u16* an = sA[(j + 1) % 3];
    const u16* bn_ = sB[(j + 1) & 1];
    readA(afQ, a_, 1); readB(bfQ, b_, 1);
    if (j + 2 < NK) stageA(j + 2);
    asm volatile("s_waitcnt lgkmcnt(8)" ::: "memory");
    __builtin_amdgcn_sched_barrier(0);
    __builtin_amdgcn_s_setprio(1);
    #pragma unroll
    for (int mf = 0; mf < 4; ++mf)
      #pragma unroll
      for (int nf = 0; nf < 4; ++nf)
        acc[mf][nf] = __builtin_amdgcn_mfma_f32_16x16x32_bf16(afP[mf], bfP[nf],
                                                              acc[mf][nf], 0, 0, 0);
    __builtin_amdgcn_s_setprio(0);
    if (j + 2 < NK) asm volatile("s_waitcnt vmcnt(4)" ::: "memory");
    else            asm volatile("s_waitcnt vmcnt(0)" ::: "memory");
    asm volatile("s_barrier" ::: "memory");
    readA(afP, an, 0); readB(bfP, bn_, 0);
    if (j + 2 < NK) stageB(j + 2);
    asm volatile("s_waitcnt lgkmcnt(8)" ::: "memory");
    __builtin_amdgcn_sched_barrier(0);
    __builtin_amdgcn_s_setprio(1);
    #pragma unroll
    for (int mf = 0; mf < 4; ++mf)
      #pragma unroll
      for (int nf = 0; nf < 4; ++nf)
        acc[mf][nf] = __builtin_amdgcn_mfma_f32_16x16x32_bf16(afQ[mf], bfQ[nf],
                                                              acc[mf][nf], 0, 0, 0);
    __builtin_amdgcn_s_setprio(0);
  }

  #pragma unroll
  for (int i = 0; i < 4; ++i) {
    #pragma unroll
    for (int j = 0; j < 4; ++j) {
      int colg = bn + wn + j * 16 + lr;
      if (bn < 1024) {  // K head, fused RoPE (block-uniform branch)
        #pragma unroll
        for (int r = 0; r < 4; ++r) {
          int row = bm + wm + i * 16 + lq * 4 + r;
          float o = rope_rot(acc[i][j][r], colg, row & 2047, cosT, sinT);
          Kout[(size_t)row * 1024 + colg] = f2bf(o);
        }
      } else {  // V -> V^T pack
        int col = colg - 1024;
        int row0 = bm + wm + i * 16 + lq * 4;
        int bb = row0 >> 11, s = row0 & 2047;
        ushort4 pk = make_ushort4(f2bf(acc[i][j][0]), f2bf(acc[i][j][1]),
                                  f2bf(acc[i][j][2]), f2bf(acc[i][j][3]));
        *(ushort4*)(Vt + ((size_t)bb * 1024 + col) * 2048 + s) = pk;
      }
    }
  }
}

// ---------- 256^2-tile GEMM v5 (best measured): read-ahead + deep slack ----------
template <int EPI, bool ROPE>
__global__ __launch_bounds__(512, 2) void gemm256(const u16* __restrict__ A,
                                                  const u16* __restrict__ Bt,
                                                  void* __restrict__ Cout,
                                                  int M, int N, int K,
                                                  const float* __restrict__ cosT,
                                                  const float* __restrict__ sinT,
                                                  float post) {
  __shared__ __attribute__((aligned(16))) u16 sA[3][256 * 64];
  __shared__ __attribute__((aligned(16))) u16 sB[2][256 * 64];
  const int tid = threadIdx.x;
  const int wid = tid >> 6, lane = tid & 63;
  const int lr = lane & 15, lq = lane >> 4;
  const int nbn = N >> 8;
  int lin = blockIdx.y * gridDim.x + blockIdx.x;
  int cpx = (gridDim.x * gridDim.y) >> 3;
  int swz = (lin & 7) * cpx + (lin >> 3);
  const int bm = (swz / nbn) * 256, bn = (swz % nbn) * 256;
  const int wrow = (wid >> 2) * 128, wcol = (wid & 3) * 64;
  const int NK = K >> 6;

  f32x4 acc[8][4] = {};

  auto stageA = [&](int j) {
    u16* dst = &sA[j % 3][0];
    #pragma unroll
    for (int c = 0; c < 4; ++c) {
      int e = (c * 512 + tid) * 8;
      int r = e >> 6, col = e & 63;
      gload_lds16(A + (size_t)(bm + r) * K + j * 64 + (col ^ ((r & 7) << 3)), dst + e);
    }
  };
  auto stageB = [&](int j) {
    u16* dst = &sB[j & 1][0];
    #pragma unroll
    for (int c = 0; c < 4; ++c) {
      int e = (c * 512 + tid) * 8;
      int r = e >> 6, col = e & 63;
      gload_lds16(Bt + (size_t)(bn + r) * K + j * 64 + (col ^ ((r & 7) << 3)), dst + e);
    }
  };
  auto readA = [&](bf16x8* af, const u16* a_, int ks) {
    #pragma unroll
    for (int mf = 0; mf < 8; ++mf) {
      int row = wrow + mf * 16 + lr;
      af[mf] = *(const bf16x8*)(a_ + row * 64 + ((ks * 32 + lq * 8) ^ ((row & 7) << 3)));
    }
  };
  auto readB = [&](bf16x8* bfv, const u16* b_, int ks) {
    #pragma unroll
    for (int nf = 0; nf < 4; ++nf) {
      int row = wcol + nf * 16 + lr;
      bfv[nf] = *(const bf16x8*)(b_ + row * 64 + ((ks * 32 + lq * 8) ^ ((row & 7) << 3)));
    }
  };

  bf16x8 afP[8], bfP[4], afQ[8], bfQ[4];

  stageB(0); stageA(0); stageA(1); stageB(1);
  asm volatile("s_waitcnt vmcnt(8)" ::: "memory");
  asm volatile("s_barrier" ::: "memory");
  readA(afP, sA[0], 0); readB(bfP, sB[0], 0);  // frags (0,0)

  for (int j = 0; j < NK; ++j) {
    const u16* a_ = sA[j % 3];
    const u16* b_ = sB[j & 1];
    const u16* an = sA[(j + 1) % 3];
    const u16* bn = sB[(j + 1) & 1];
    readA(afQ, a_, 1); readB(bfQ, b_, 1);
    if (j + 2 < NK) stageA(j + 2);
    asm volatile("s_waitcnt lgkmcnt(12)" ::: "memory");
    __builtin_amdgcn_sched_barrier(0);
    __builtin_amdgcn_s_setprio(1);
    #pragma unroll
    for (int mf = 0; mf < 8; ++mf)
      #pragma unroll
      for (int nf = 0; nf < 4; ++nf)
        acc[mf][nf] = __builtin_amdgcn_mfma_f32_16x16x32_bf16(afP[mf], bfP[nf],
                                                              acc[mf][nf], 0, 0, 0);
    __builtin_amdgcn_s_setprio(0);
    if (j + 2 < NK) asm volatile("s_waitcnt vmcnt(4)" ::: "memory");
    else            asm volatile("s_waitcnt vmcnt(0)" ::: "memory");
    asm volatile("s_barrier" ::: "memory");
    readA(afP, an, 0); readB(bfP, bn, 0);
    if (j + 2 < NK) stageB(j + 2);
    asm volatile("s_waitcnt lgkmcnt(12)" ::: "memory");
    __builtin_amdgcn_sched_barrier(0);
    __builtin_amdgcn_s_setprio(1);
    #pragma unroll
    for (int mf = 0; mf < 8; ++mf)
      #pragma unroll
      for (int nf = 0; nf < 4; ++nf)
        acc[mf][nf] = __builtin_amdgcn_mfma_f32_16x16x32_bf16(afQ[mf], bfQ[nf],
                                                              acc[mf][nf], 0, 0, 0);
    __builtin_amdgcn_s_setprio(0);
  }

  #pragma unroll
  for (int mf = 0; mf < 8; ++mf) {
    #pragma unroll
    for (int nf = 0; nf < 4; ++nf) {
      #pragma unroll
      for (int r = 0; r < 4; ++r) {
        int row = bm + wrow + mf * 16 + lq * 4 + r;
        int col = bn + wcol + nf * 16 + lr;
        if (ROPE) {
          float o = rope_rot(acc[mf][nf][r], col, row & 2047, cosT, sinT);
          ((u16*)Cout)[(size_t)row * N + col] = f2bf(o * post);
        } else if (EPI == 0) {
          ((u16*)Cout)[(size_t)row * N + col] = f2bf(acc[mf][nf][r]);
        } else {
          ((float*)Cout)[(size_t)row * N + col] = acc[mf][nf][r];
        }
      }
    }
  }
}

// ---------- flash attention (r17-best): swapped-QK, in-register P-pack ----------
__global__ __launch_bounds__(256, 2) void attn_kernel(const u16* __restrict__ Q,
                                                      const u16* __restrict__ Kb,
                                                      const u16* __restrict__ Vt,
                                                      u16* __restrict__ O) {
  __shared__ __attribute__((aligned(16))) u16 sK[2][64 * 128];
  __shared__ __attribute__((aligned(16))) u16 sV[2][128 * 64];
  __shared__ __attribute__((aligned(16))) u16 sP[4][16 * 64];
  const int tid = threadIdx.x;
  const int wave = tid >> 6, lane = tid & 63;
  const int lr = lane & 15, lq = lane >> 4;
  const int p = blockIdx.x & 15;
  const int h = (blockIdx.x >> 4) & 31;
  const int b = blockIdx.x >> 9;
  const int kvh = h >> 2;
  const int qtA = p, qtB = 31 - p;
  const int q0A = qtA * 64 + wave * 16;
  const int q0B = qtB * 64 + wave * 16;
  const float NOFF = ATTN_NOFF;

  bf16x8 qfA[4], qfB[4];
  {
    const u16* qa = Q + (size_t)(b * 2048 + q0A + lr) * 4096 + h * 128 + lq * 8;
    const u16* qb = Q + (size_t)(b * 2048 + q0B + lr) * 4096 + h * 128 + lq * 8;
    #pragma unroll
    for (int ks = 0; ks < 4; ++ks) {
      qfA[ks] = *(const bf16x8*)(qa + ks * 32);
      qfB[ks] = *(const bf16x8*)(qb + ks * 32);
    }
  }

  const u16* kbase = Kb + (size_t)b * 2048 * 1024 + kvh * 128;
  const u16* vbase = Vt + (size_t)(b * 1024 + kvh * 128) * 2048;

  auto stage = [&](int kt, int bsel) {
    #pragma unroll
    for (int c = 0; c < 4; ++c) {
      int chunk = wave * 4 + c;
      int eo = chunk * 512 + lane * 8;
      int rk = eo >> 7, ck = eo & 127;
      int cks = ck ^ ((rk & 7) << 3);
      gload_lds16(kbase + (size_t)(kt * 64 + rk) * 1024 + cks,
                  (u16*)sK[bsel] + chunk * 512);
      int rv = eo >> 6, cv = eo & 63;
      int cvs = cv ^ ((rv & 7) << 3);
      gload_lds16(vbase + (size_t)rv * 2048 + kt * 64 + cvs,
                  (u16*)sV[bsel] + chunk * 512);
    }
  };

  f32x4 oA[8] = {}, oB[8] = {};
  float lA = 0.f, lB = 0.f;  // per-lane partial row-sum for q = lr (16 keys/lane/tile)

  stage(0, 0);
  __syncthreads();
  int buf = 0;
  for (int kt = 0; kt <= qtB; ++kt) {
    if (kt < qtB) stage(kt + 1, buf ^ 1);
    const u16* kb_ = sK[buf];
    const u16* vb_ = sV[buf];
    const bool doA = (kt <= qtA);

    f32x4 sAacc[4], sBacc[4];
    #pragma unroll
    for (int nf = 0; nf < 4; ++nf) {
      sAacc[nf] = (f32x4){NOFF, NOFF, NOFF, NOFF};
      sBacc[nf] = (f32x4){NOFF, NOFF, NOFF, NOFF};
    }
    __builtin_amdgcn_s_setprio(1);
    #pragma unroll
    for (int ks = 0; ks < 4; ++ks) {
      bf16x8 kf[4];
      #pragma unroll
      for (int nf = 0; nf < 4; ++nf) {
        int row = nf * 16 + lr;
        kf[nf] = *(const bf16x8*)(kb_ + row * 128 + ((ks * 32 + lq * 8) ^ ((row & 7) << 3)));
      }
      // swapped: lane holds S[q=lr][key=nf*16+lq*4+r]
      #pragma unroll
      for (int nf = 0; nf < 4; ++nf)
        sBacc[nf] = __builtin_amdgcn_mfma_f32_16x16x32_bf16(kf[nf], qfB[ks], sBacc[nf], 0, 0, 0);
      if (doA) {
        #pragma unroll
        for (int nf = 0; nf < 4; ++nf)
          sAacc[nf] = __builtin_amdgcn_mfma_f32_16x16x32_bf16(kf[nf], qfA[ks], sAacc[nf], 0, 0, 0);
      }
    }
    __builtin_amdgcn_s_setprio(0);

    auto sm_pv = [&](f32x4* sacc, float& lsum, f32x4* o, int qt, int q0) {
      float ls = 0.f;
      const bool diag = (kt == qt);
      #pragma unroll
      for (int nf = 0; nf < 4; ++nf) {
        float v0 = ATTN_EXP(sacc[nf][0]);
        float v1 = ATTN_EXP(sacc[nf][1]);
        float v2 = ATTN_EXP(sacc[nf][2]);
        float v3 = ATTN_EXP(sacc[nf][3]);
        if (diag) {
          int kb0 = kt * 64 + nf * 16 + lq * 4;
          int q = q0 + lr;
          if (kb0 + 0 > q) v0 = 0.f;
          if (kb0 + 1 > q) v1 = 0.f;
          if (kb0 + 2 > q) v2 = 0.f;
          if (kb0 + 3 > q) v3 = 0.f;
        }
        ls += (v0 + v1) + (v2 + v3);
        uint32_t p01, p23;
        asm("v_cvt_pk_bf16_f32 %0, %1, %2" : "=v"(p01) : "v"(v0), "v"(v1));
        asm("v_cvt_pk_bf16_f32 %0, %1, %2" : "=v"(p23) : "v"(v2), "v"(v3));
        uint32_t* dst = (uint32_t*)((char*)sP[wave] +
                          ((lr * 128 + nf * 32 + lq * 8) ^ ((lr & 7) << 4)));
        dst[0] = p01;
        dst[1] = p23;
      }
      lsum += ls;
      __builtin_amdgcn_s_setprio(1);
      #pragma unroll
      for (int ks = 0; ks < 2; ++ks) {
        bf16x8 pa = *(const bf16x8*)((const char*)sP[wave] +
                        ((lr * 128 + ks * 64 + lq * 16) ^ ((lr & 7) << 4)));
        #pragma unroll
        for (int df = 0; df < 8; ++df) {
          int row = df * 16 + lr;
          bf16x8 vb = *(const bf16x8*)(vb_ + row * 64 + ((ks * 32 + lq * 8) ^ ((row & 7) << 3)));
          o[df] = __builtin_amdgcn_mfma_f32_16x16x32_bf16(pa, vb, o[df], 0, 0, 0);
        }
      }
      __builtin_amdgcn_s_setprio(0);
    };

    if (doA) sm_pv(sAacc, lA, oA, qtA, q0A);
    sm_pv(sBacc, lB, oB, qtB, q0B);

    __syncthreads();
    buf ^= 1;
  }

  float tA = lA, tB = lB;
  tA += __shfl_xor(tA, 16, 64); tB += __shfl_xor(tB, 16, 64);
  tA += __shfl_xor(tA, 32, 64); tB += __shfl_xor(tB, 32, 64);
  tA = 1.f / tA; tB = 1.f / tB;
  float liA[4], liB[4];
  #pragma unroll
  for (int r = 0; r < 4; ++r) {
    liA[r] = __shfl(tA, lq * 4 + r, 64);
    liB[r] = __shfl(tB, lq * 4 + r, 64);
  }
  #pragma unroll
  for (int df = 0; df < 8; ++df) {
    #pragma unroll
    for (int r = 0; r < 4; ++r) {
      int iqA = q0A + lq * 4 + r;
      int iqB = q0B + lq * 4 + r;
      O[(size_t)(b * 2048 + iqA) * 4096 + h * 128 + df * 16 + lr] = f2bf(oA[df][r] * liA[r]);
      O[(size_t)(b * 2048 + iqB) * 4096 + h * 128 + df * 16 + lr] = f2bf(oB[df][r] * liB[r]);
    }
  }
}

extern "C" void kernel_launch(void* const* d_in, const int* in_sizes, int n_in,
                              void* d_out, int out_size, void* d_ws, size_t ws_size,
                              hipStream_t stream) {
  (void)in_sizes; (void)n_in; (void)out_size;
  const float* x    = (const float*)d_in[0];
  const float* cosT = (const float*)d_in[1];
  const float* sinT = (const float*)d_in[2];
  const float* wq   = (const float*)d_in[4];
  const float* wk   = (const float*)d_in[5];
  const float* wv   = (const float*)d_in[6];
  const float* wo   = (const float*)d_in[7];
  float* out = (float*)d_out;
  char* ws = (char*)d_ws;

  const size_t WS_NEEDED = 201326592;  // 192 MiB
  if (ws_size < WS_NEEDED) return;

  u16* xb   = (u16*)(ws);                 // [4096][4096]
  u16* wqt  = (u16*)(ws + 33554432ULL);   // [4096][4096]
  u16* wkvt = (u16*)(ws + 67108864ULL);   // [2048][4096]
  u16* wot  = (u16*)(ws + 83886080ULL);   // [4096][4096]
  u16* Qb   = (u16*)(ws + 117440512ULL);  // [4096][4096]
  u16* Kbf  = (u16*)(ws + 150994944ULL);  // [4096][1024]
  u16* Vt   = (u16*)(ws + 159383552ULL);  // [2][1024][2048]
  u16* Ob   = (u16*)(ws + 167772160ULL);  // [4096][4096]

  const float QSC = ATTN_QSC;  // pairs with ATTN_NOFF / ATTN_EXP

  cvt_kernel<<<16384, 256, 0, stream>>>(x, xb);
  // merged transposes: wq+wo (one launch), wk+wv (one launch, both into wkvt)
  transpose_cvt2<<<dim3(128, 256), dim3(32, 8), 0, stream>>>(wq, wqt, wo, wot,
                                                             4096, 4096, 128);
  transpose_cvt2<<<dim3(32, 256), dim3(32, 8), 0, stream>>>(wk, wkvt,
                                                            wv, wkvt + 1024ULL * 4096,
                                                            4096, 1024, 128);

  // Q projection with fused RoPE + prescale
  gemm256<0, true><<<dim3(16, 16), 512, 0, stream>>>(xb, wqt, Qb, 4096, 4096, 4096,
                                                     cosT, sinT, QSC);
  // fused K (RoPE) + V (transposed) projections
  gemm_kv<<<dim3(16, 32), 256, 0, stream>>>(xb, wkvt, Kbf, Vt, cosT, sinT);

  attn_kernel<<<1024, 256, 0, stream>>>(Qb, Kbf, Vt, Ob);

  gemm256<2, false><<<dim3(16, 16), 512, 0, stream>>>(Ob, wot, out, 4096, 4096, 4096,
                                                      nullptr, nullptr, 1.0f);
}